// Round 18
// baseline (217.683 us; speedup 1.0000x reference)
//
#include <hip/hip_runtime.h>
#include <math.h>

#define BATCH 1024
#define NV 5023
#define NJ 5
#define K1 150
#define K2 36
#define KTOT 186
#define MCOLS (NV*3)        // 15069
#define NCHUNK 80
#define CHUNKV 63           // 80*63 = 5040 >= 5023

typedef __attribute__((ext_vector_type(4))) float floatx4;

// ws layout (float offsets). Total 255200 floats = 1.02 MB (< proven 1.38 MB).
#define WS_JSD     0                 // 2265 (pad 2272)
#define WS_RELTF   2272              // 61440 -> 63712
#define WS_Y       63712             // 1024 -> 64736
#define WS_AT      64736             // At[186][1024] = 190464 -> 255200
#define WS_PARTIAL 64736             // aliases At: 80*5*453 = 181200 (dead before k2)

__device__ __forceinline__ void rodrigues(const float* rv, float* R) {
  const float ex = rv[0]+1e-8f, ey = rv[1]+1e-8f, ez = rv[2]+1e-8f;
  const float angle = sqrtf(ex*ex + ey*ey + ez*ez);
  const float inv = 1.0f/angle;
  const float nx = rv[0]*inv, ny = rv[1]*inv, nz = rv[2]*inv;
  const float s = sinf(angle), c = cosf(angle);
  const float omc = 1.0f - c;
  R[0] = 1.0f - omc*(ny*ny+nz*nz);
  R[1] = -s*nz + omc*nx*ny;
  R[2] =  s*ny + omc*nx*nz;
  R[3] =  s*nz + omc*nx*ny;
  R[4] = 1.0f - omc*(nx*nx+nz*nz);
  R[5] = -s*nx + omc*ny*nz;
  R[6] = -s*ny + omc*nx*nz;
  R[7] =  s*nx + omc*ny*nz;
  R[8] = 1.0f - omc*(nx*nx+ny*ny);
}

// ---- k1 (one-pass over j): shapedirs read ONCE
__launch_bounds__(512)
__global__ void k1_jsd_partial(const float* __restrict__ jreg, const float* __restrict__ shdirs,
                               const float* __restrict__ vtemp, float* __restrict__ partial) {
  const int chunk = blockIdx.x;
  const int t = threadIdx.x;
  if (t >= 453) return;
  const int v0 = chunk*CHUNKV;
  const int v1 = (v0 + CHUNKV < NV) ? v0 + CHUNKV : NV;
  float acc[5] = {0.f,0.f,0.f,0.f,0.f};
  if (t < 450) {
    for (int v = v0; v < v1; ++v) {
      const float sv = shdirs[(size_t)v*450 + t];
      #pragma unroll
      for (int j=0;j<5;++j) acc[j] = fmaf(jreg[j*NV + v], sv, acc[j]);
    }
  } else {
    const int c = t - 450;
    for (int v = v0; v < v1; ++v) {
      const float sv = vtemp[v*3 + c];
      #pragma unroll
      for (int j=0;j<5;++j) acc[j] = fmaf(jreg[j*NV + v], sv, acc[j]);
    }
  }
  #pragma unroll
  for (int j=0;j<5;++j)
    partial[(size_t)(chunk*NJ + j)*453 + t] = acc[j];
}

__launch_bounds__(256)
__global__ void k1b_jsd_reduce(const float* __restrict__ partial, float* __restrict__ jsd) {
  const int i = blockIdx.x*256 + threadIdx.x;
  if (i >= NJ*453) return;
  float s = 0.0f;
  for (int c = 0; c < NCHUNK; ++c) s += partial[(size_t)c*(NJ*453) + i];
  jsd[i] = s;
}

// ---- k2: pose pipeline; emits TRANSPOSED A: At[k][b]. Betas loaded vectorized.
__launch_bounds__(256)
__global__ void k2_pose(const float* __restrict__ shape, const float* __restrict__ expr,
                        const float* __restrict__ pose, const float* __restrict__ neck,
                        const float* __restrict__ eye, const float* __restrict__ jsd,
                        float* __restrict__ At, float* __restrict__ reltf,
                        int* __restrict__ yidx) {
  const int b = blockIdx.x*256 + threadIdx.x;
  if (b >= BATCH) return;

  float fp[15];
  fp[0]=pose[b*6+0]; fp[1]=pose[b*6+1]; fp[2]=pose[b*6+2];
  fp[3]=neck[0];     fp[4]=neck[1];     fp[5]=neck[2];
  fp[6]=pose[b*6+3]; fp[7]=pose[b*6+4]; fp[8]=pose[b*6+5];
  #pragma unroll
  for (int i=0;i<6;++i) fp[9+i] = eye[i];

  float R[5][9];
  #pragma unroll
  for (int j=0;j<5;++j) rodrigues(&fp[j*3], R[j]);

  for (int l=0;l<100;++l) At[(size_t)l*BATCH + b] = shape[(size_t)b*100 + l];
  for (int l=0;l<50;++l)  At[(size_t)(100+l)*BATCH + b] = expr[(size_t)b*50 + l];
  #pragma unroll
  for (int jj=0;jj<4;++jj)
    #pragma unroll
    for (int rc=0;rc<9;++rc)
      At[(size_t)(K1 + jj*9 + rc)*BATCH + b] = R[1+jj][rc] - ((rc==0||rc==4||rc==8)?1.0f:0.0f);

  float jac[15];
  #pragma unroll
  for (int jc=0;jc<15;++jc) jac[jc] = jsd[(jc/3)*453 + 450 + (jc%3)];
  {
    const floatx4* sh4 = reinterpret_cast<const floatx4*>(shape + (size_t)b*100);
    for (int l4=0; l4<25; ++l4) {
      const floatx4 s4 = sh4[l4];
      #pragma unroll
      for (int u=0;u<4;++u) {
        const int l = l4*4 + u;
        const float bv = s4[u];
        #pragma unroll
        for (int jc=0;jc<15;++jc)
          jac[jc] = fmaf(jsd[(jc/3)*453 + (jc%3)*150 + l], bv, jac[jc]);
      }
    }
    const float2* ex2 = reinterpret_cast<const float2*>(expr + (size_t)b*50);
    for (int l2=0; l2<25; ++l2) {
      const float2 e2 = ex2[l2];
      #pragma unroll
      for (int u=0;u<2;++u) {
        const int l = 100 + l2*2 + u;
        const float bv = (u==0) ? e2.x : e2.y;
        #pragma unroll
        for (int jc=0;jc<15;++jc)
          jac[jc] = fmaf(jsd[(jc/3)*453 + (jc%3)*150 + l], bv, jac[jc]);
      }
    }
  }

  float C[5][12];
  #pragma unroll
  for (int r=0;r<3;++r) {
    C[0][r*4+0]=R[0][r*3+0]; C[0][r*4+1]=R[0][r*3+1]; C[0][r*4+2]=R[0][r*3+2];
    C[0][r*4+3]=jac[r];
  }
  const int par[5] = {-1,0,1,1,1};
  #pragma unroll
  for (int i=1;i<5;++i) {
    const int p = par[i];
    const float rj0 = jac[i*3+0]-jac[p*3+0];
    const float rj1 = jac[i*3+1]-jac[p*3+1];
    const float rj2 = jac[i*3+2]-jac[p*3+2];
    #pragma unroll
    for (int r=0;r<3;++r) {
      const float c0=C[p][r*4+0], c1=C[p][r*4+1], c2=C[p][r*4+2], c3=C[p][r*4+3];
      C[i][r*4+0] = c0*R[i][0] + c1*R[i][3] + c2*R[i][6];
      C[i][r*4+1] = c0*R[i][1] + c1*R[i][4] + c2*R[i][7];
      C[i][r*4+2] = c0*R[i][2] + c1*R[i][5] + c2*R[i][8];
      C[i][r*4+3] = c0*rj0 + c1*rj1 + c2*rj2 + c3;
    }
  }

  float* rt = reltf + (size_t)b*60;
  #pragma unroll
  for (int j=0;j<5;++j) {
    const float jx=jac[j*3+0], jy=jac[j*3+1], jz=jac[j*3+2];
    #pragma unroll
    for (int r=0;r<3;++r) {
      const float m0=C[j][r*4+0], m1=C[j][r*4+1], m2=C[j][r*4+2], m3=C[j][r*4+3];
      rt[j*12+r*4+0]=m0; rt[j*12+r*4+1]=m1; rt[j*12+r*4+2]=m2;
      rt[j*12+r*4+3]=m3 - (m0*jx + m1*jy + m2*jz);
    }
  }

  const float c00=R[1][0], c10=R[1][3], c20=R[1][6];
  const float r00 = R[0][0]*c00 + R[0][1]*c10 + R[0][2]*c20;
  const float r10 = R[0][3]*c00 + R[0][4]*c10 + R[0][5]*c20;
  const float r20 = R[0][6]*c00 + R[0][7]*c10 + R[0][8]*c20;
  const float sy = sqrtf(r00*r00 + r10*r10);
  const float yang = atan2f(-r20, sy) * 57.29577951308232f;
  int y = (int)rintf(fminf(yang, 39.0f));
  if (y < 0) y = (y < -39) ? 78 : (39 - y);
  yidx[b] = y;
}

// ---- k3 v16: NO LDS, NO BARRIERS. 128 batches x 64 verts, 256 threads.
// thread = vert vl x 32 batches. A: wave-uniform s_load (lgkmcnt only).
// B: per-lane float2 global loads from shdirs rows (k-contiguous, vmcnt) into
// 10-row register chunks; pose via strided dword loads. Compiler pipelines
// freely across chunks (no syncthreads to block hoisting). acc order == r15.
__launch_bounds__(256, 3)
__global__ void k3_valu(const float* __restrict__ At, const float* __restrict__ shdirs,
                        const float* __restrict__ pdirs, const float* __restrict__ vtemp,
                        const float* __restrict__ lbsw, const float* __restrict__ reltf,
                        float* __restrict__ vout) {
  const int t  = threadIdx.x;
  const int vl = t & 63;
  const int bg = t >> 6;             // 0..3, wave-uniform
  const int v0 = blockIdx.x * 64;
  const int b0 = blockIdx.y * 128;
  const int aoff = __builtin_amdgcn_readfirstlane(b0 + bg*32);

  const int v  = v0 + vl;
  const int vc = (v < NV) ? v : NV-1;
  const float* brow0 = shdirs + (size_t)(3*vc+0)*K1;
  const float* brow1 = shdirs + (size_t)(3*vc+1)*K1;
  const float* brow2 = shdirs + (size_t)(3*vc+2)*K1;

  float acc[32][3] = {};

  // shape part: 15 chunks of 10 k-rows
  #pragma unroll 1
  for (int g=0; g<15; ++g) {
    const int k0 = g*10;
    float ba[10], bb[10], bc[10];
    #pragma unroll
    for (int q=0;q<5;++q) {
      const float2 f0 = *reinterpret_cast<const float2*>(brow0 + k0 + 2*q);
      const float2 f1 = *reinterpret_cast<const float2*>(brow1 + k0 + 2*q);
      const float2 f2 = *reinterpret_cast<const float2*>(brow2 + k0 + 2*q);
      ba[2*q]=f0.x; ba[2*q+1]=f0.y;
      bb[2*q]=f1.x; bb[2*q+1]=f1.y;
      bc[2*q]=f2.x; bc[2*q+1]=f2.y;
    }
    #pragma unroll
    for (int kk=0; kk<10; ++kk) {
      const float* ap = At + (size_t)(k0+kk)*BATCH + aoff;   // wave-uniform -> s_load
      #pragma unroll
      for (int i=0;i<32;++i) {
        const float ai = ap[i];
        acc[i][0] = fmaf(ai, ba[kk], acc[i][0]);
        acc[i][1] = fmaf(ai, bb[kk], acc[i][1]);
        acc[i][2] = fmaf(ai, bc[kk], acc[i][2]);
      }
    }
  }
  // pose part: 6 chunks of 6 k-rows (pdirs is k-major: [k][m])
  #pragma unroll 1
  for (int g=0; g<6; ++g) {
    const int kp0 = g*6;             // 0..30
    float ba[6], bb[6], bc[6];
    #pragma unroll
    for (int kk=0;kk<6;++kk) {
      const float* prow = pdirs + (size_t)(kp0+kk)*MCOLS + 3*vc;
      ba[kk] = prow[0]; bb[kk] = prow[1]; bc[kk] = prow[2];
    }
    #pragma unroll
    for (int kk=0; kk<6; ++kk) {
      const float* ap = At + (size_t)(K1+kp0+kk)*BATCH + aoff;
      #pragma unroll
      for (int i=0;i<32;++i) {
        const float ai = ap[i];
        acc[i][0] = fmaf(ai, ba[kk], acc[i][0]);
        acc[i][1] = fmaf(ai, bb[kk], acc[i][1]);
        acc[i][2] = fmaf(ai, bc[kk], acc[i][2]);
      }
    }
  }

  // epilogue: FULLY UNROLLED; rel_tf via wave-uniform scalar loads; LBS + store
  if (v < NV) {
    float w5[5];
    #pragma unroll
    for (int j=0;j<5;++j) w5[j] = lbsw[(size_t)v*5 + j];
    const float tx = vtemp[(size_t)v*3+0];
    const float ty = vtemp[(size_t)v*3+1];
    const float tz = vtemp[(size_t)v*3+2];
    #pragma unroll
    for (int i=0;i<32;++i) {
      const float* rl = reltf + (size_t)(aoff + i)*60;   // wave-uniform -> s_load
      const float vx = acc[i][0]+tx, vy = acc[i][1]+ty, vz = acc[i][2]+tz;
      float o[3];
      #pragma unroll
      for (int r=0;r<3;++r) {
        float a0=0.f,a1=0.f,a2=0.f,a3=0.f;
        #pragma unroll
        for (int j=0;j<5;++j) {
          a0 = fmaf(w5[j], rl[j*12+r*4+0], a0);
          a1 = fmaf(w5[j], rl[j*12+r*4+1], a1);
          a2 = fmaf(w5[j], rl[j*12+r*4+2], a2);
          a3 = fmaf(w5[j], rl[j*12+r*4+3], a3);
        }
        o[r] = fmaf(a0, vx, fmaf(a1, vy, fmaf(a2, vz, a3)));
      }
      float* dst = vout + ((size_t)(aoff + i)*NV + v)*3;
      dst[0]=o[0]; dst[1]=o[1]; dst[2]=o[2];
    }
  }
}

// ---- k4: landmarks
__launch_bounds__(192)
__global__ void k4_landmarks(const float* __restrict__ verts, const int* __restrict__ faces,
                             const int* __restrict__ lmkf, const float* __restrict__ lmkb,
                             const int* __restrict__ dynf, const float* __restrict__ dynb,
                             const int* __restrict__ fullf, const float* __restrict__ fullb,
                             const int* __restrict__ yidx, float* __restrict__ out2d,
                             float* __restrict__ out3d) {
  const int b = blockIdx.x;
  const int t = threadIdx.x;
  if (t >= 136) return;
  const int which = t >= 68;
  const int i = which ? (t-68) : t;
  int fidx; float bw0,bw1,bw2;
  if (!which) {
    if (i < 17) {
      const int y = yidx[b];
      fidx = dynf[y*17 + i];
      const float* p = dynb + ((size_t)y*17 + i)*3;
      bw0=p[0]; bw1=p[1]; bw2=p[2];
    } else {
      fidx = lmkf[i-17];
      const float* p = lmkb + (size_t)(i-17)*3;
      bw0=p[0]; bw1=p[1]; bw2=p[2];
    }
  } else {
    fidx = fullf[i];
    const float* p = fullb + (size_t)i*3;
    bw0=p[0]; bw1=p[1]; bw2=p[2];
  }
  const int t0 = faces[fidx*3+0], t1 = faces[fidx*3+1], t2 = faces[fidx*3+2];
  const float* vb = verts + (size_t)b*NV*3;
  float* dst = (which ? out3d : out2d) + ((size_t)b*68 + i)*3;
  #pragma unroll
  for (int c=0;c<3;++c)
    dst[c] = vb[(size_t)t0*3+c]*bw0 + vb[(size_t)t1*3+c]*bw1 + vb[(size_t)t2*3+c]*bw2;
}

extern "C" void kernel_launch(void* const* d_in, const int* in_sizes, int n_in,
                              void* d_out, int out_size, void* d_ws, size_t ws_size,
                              hipStream_t stream) {
  const float* shape = (const float*)d_in[0];
  const float* expr  = (const float*)d_in[1];
  const float* pose  = (const float*)d_in[2];
  const float* vtemp = (const float*)d_in[3];
  const float* shdirs= (const float*)d_in[4];
  const float* pdirs = (const float*)d_in[5];
  const float* jreg  = (const float*)d_in[6];
  const float* lbsw  = (const float*)d_in[7];
  const float* neck  = (const float*)d_in[8];
  const float* eye   = (const float*)d_in[9];
  const int*   faces = (const int*)d_in[10];
  const int*   lmkf  = (const int*)d_in[11];
  const float* lmkb  = (const float*)d_in[12];
  const int*   dynf  = (const int*)d_in[13];
  const float* dynb  = (const float*)d_in[14];
  const int*   fullf = (const int*)d_in[15];
  const float* fullb = (const float*)d_in[16];

  float* wsf = (float*)d_ws;
  float* jsd     = wsf + WS_JSD;
  float* reltf   = wsf + WS_RELTF;
  int*   yidx    = (int*)(wsf + WS_Y);
  float* At      = wsf + WS_AT;
  float* partial = wsf + WS_PARTIAL;   // aliases At (dead before k2 writes At)

  float* vout  = (float*)d_out;
  float* out2d = vout + (size_t)BATCH*NV*3;
  float* out3d = out2d + (size_t)BATCH*68*3;

  hipLaunchKernelGGL(k1_jsd_partial, dim3(NCHUNK), dim3(512), 0, stream,
                     jreg, shdirs, vtemp, partial);
  hipLaunchKernelGGL(k1b_jsd_reduce, dim3(9), dim3(256), 0, stream, partial, jsd);
  hipLaunchKernelGGL(k2_pose, dim3(4), dim3(256), 0, stream,
                     shape, expr, pose, neck, eye, jsd, At, reltf, yidx);
  hipLaunchKernelGGL(k3_valu, dim3(80, BATCH/128), dim3(256), 0, stream,
                     At, shdirs, pdirs, vtemp, lbsw, reltf, vout);
  hipLaunchKernelGGL(k4_landmarks, dim3(BATCH), dim3(192), 0, stream,
                     vout, faces, lmkf, lmkb, dynf, dynb, fullf, fullb, yidx, out2d, out3d);
}

// Round 19
// 179.284 us; speedup vs baseline: 1.2142x; 1.2142x over previous
//
#include <hip/hip_runtime.h>
#include <math.h>

#define BATCH 1024
#define NV 5023
#define NJ 5
#define K1 150
#define K2 36
#define KTOT 186
#define MCOLS (NV*3)        // 15069
#define NCHUNK 80
#define CHUNKV 63           // 80*63 = 5040 >= 5023

typedef __attribute__((ext_vector_type(4))) float floatx4;

// ws layout (float offsets). Total 255200 floats = 1.02 MB (< proven 1.38 MB).
#define WS_JSD     0                 // 2265 (pad 2272)
#define WS_RELTF   2272              // 61440 -> 63712
#define WS_Y       63712             // 1024 -> 64736
#define WS_AT      64736             // At[186][1024] = 190464 -> 255200
#define WS_PARTIAL 64736             // aliases At: 80*5*453 = 181200 (dead before k2)

__device__ __forceinline__ void rodrigues(const float* rv, float* R) {
  const float ex = rv[0]+1e-8f, ey = rv[1]+1e-8f, ez = rv[2]+1e-8f;
  const float angle = sqrtf(ex*ex + ey*ey + ez*ez);
  const float inv = 1.0f/angle;
  const float nx = rv[0]*inv, ny = rv[1]*inv, nz = rv[2]*inv;
  const float s = sinf(angle), c = cosf(angle);
  const float omc = 1.0f - c;
  R[0] = 1.0f - omc*(ny*ny+nz*nz);
  R[1] = -s*nz + omc*nx*ny;
  R[2] =  s*ny + omc*nx*nz;
  R[3] =  s*nz + omc*nx*ny;
  R[4] = 1.0f - omc*(nx*nx+nz*nz);
  R[5] = -s*nx + omc*ny*nz;
  R[6] = -s*ny + omc*nx*nz;
  R[7] =  s*nx + omc*ny*nz;
  R[8] = 1.0f - omc*(nx*nx+ny*ny);
}

// ---- k1 (one-pass over j): shapedirs read ONCE
__launch_bounds__(512)
__global__ void k1_jsd_partial(const float* __restrict__ jreg, const float* __restrict__ shdirs,
                               const float* __restrict__ vtemp, float* __restrict__ partial) {
  const int chunk = blockIdx.x;
  const int t = threadIdx.x;
  if (t >= 453) return;
  const int v0 = chunk*CHUNKV;
  const int v1 = (v0 + CHUNKV < NV) ? v0 + CHUNKV : NV;
  float acc[5] = {0.f,0.f,0.f,0.f,0.f};
  if (t < 450) {
    for (int v = v0; v < v1; ++v) {
      const float sv = shdirs[(size_t)v*450 + t];
      #pragma unroll
      for (int j=0;j<5;++j) acc[j] = fmaf(jreg[j*NV + v], sv, acc[j]);
    }
  } else {
    const int c = t - 450;
    for (int v = v0; v < v1; ++v) {
      const float sv = vtemp[v*3 + c];
      #pragma unroll
      for (int j=0;j<5;++j) acc[j] = fmaf(jreg[j*NV + v], sv, acc[j]);
    }
  }
  #pragma unroll
  for (int j=0;j<5;++j)
    partial[(size_t)(chunk*NJ + j)*453 + t] = acc[j];
}

__launch_bounds__(256)
__global__ void k1b_jsd_reduce(const float* __restrict__ partial, float* __restrict__ jsd) {
  const int i = blockIdx.x*256 + threadIdx.x;
  if (i >= NJ*453) return;
  float s = 0.0f;
  for (int c = 0; c < NCHUNK; ++c) s += partial[(size_t)c*(NJ*453) + i];
  jsd[i] = s;
}

// ---- k2: pose pipeline; emits TRANSPOSED A: At[k][b]. Betas loaded vectorized.
__launch_bounds__(256)
__global__ void k2_pose(const float* __restrict__ shape, const float* __restrict__ expr,
                        const float* __restrict__ pose, const float* __restrict__ neck,
                        const float* __restrict__ eye, const float* __restrict__ jsd,
                        float* __restrict__ At, float* __restrict__ reltf,
                        int* __restrict__ yidx) {
  const int b = blockIdx.x*256 + threadIdx.x;
  if (b >= BATCH) return;

  float fp[15];
  fp[0]=pose[b*6+0]; fp[1]=pose[b*6+1]; fp[2]=pose[b*6+2];
  fp[3]=neck[0];     fp[4]=neck[1];     fp[5]=neck[2];
  fp[6]=pose[b*6+3]; fp[7]=pose[b*6+4]; fp[8]=pose[b*6+5];
  #pragma unroll
  for (int i=0;i<6;++i) fp[9+i] = eye[i];

  float R[5][9];
  #pragma unroll
  for (int j=0;j<5;++j) rodrigues(&fp[j*3], R[j]);

  for (int l=0;l<100;++l) At[(size_t)l*BATCH + b] = shape[(size_t)b*100 + l];
  for (int l=0;l<50;++l)  At[(size_t)(100+l)*BATCH + b] = expr[(size_t)b*50 + l];
  #pragma unroll
  for (int jj=0;jj<4;++jj)
    #pragma unroll
    for (int rc=0;rc<9;++rc)
      At[(size_t)(K1 + jj*9 + rc)*BATCH + b] = R[1+jj][rc] - ((rc==0||rc==4||rc==8)?1.0f:0.0f);

  // joints: betas loaded as float4/float2; FP order unchanged
  float jac[15];
  #pragma unroll
  for (int jc=0;jc<15;++jc) jac[jc] = jsd[(jc/3)*453 + 450 + (jc%3)];
  {
    const floatx4* sh4 = reinterpret_cast<const floatx4*>(shape + (size_t)b*100);
    for (int l4=0; l4<25; ++l4) {
      const floatx4 s4 = sh4[l4];
      #pragma unroll
      for (int u=0;u<4;++u) {
        const int l = l4*4 + u;
        const float bv = s4[u];
        #pragma unroll
        for (int jc=0;jc<15;++jc)
          jac[jc] = fmaf(jsd[(jc/3)*453 + (jc%3)*150 + l], bv, jac[jc]);
      }
    }
    const float2* ex2 = reinterpret_cast<const float2*>(expr + (size_t)b*50);
    for (int l2=0; l2<25; ++l2) {
      const float2 e2 = ex2[l2];
      #pragma unroll
      for (int u=0;u<2;++u) {
        const int l = 100 + l2*2 + u;
        const float bv = (u==0) ? e2.x : e2.y;
        #pragma unroll
        for (int jc=0;jc<15;++jc)
          jac[jc] = fmaf(jsd[(jc/3)*453 + (jc%3)*150 + l], bv, jac[jc]);
      }
    }
  }

  float C[5][12];
  #pragma unroll
  for (int r=0;r<3;++r) {
    C[0][r*4+0]=R[0][r*3+0]; C[0][r*4+1]=R[0][r*3+1]; C[0][r*4+2]=R[0][r*3+2];
    C[0][r*4+3]=jac[r];
  }
  const int par[5] = {-1,0,1,1,1};
  #pragma unroll
  for (int i=1;i<5;++i) {
    const int p = par[i];
    const float rj0 = jac[i*3+0]-jac[p*3+0];
    const float rj1 = jac[i*3+1]-jac[p*3+1];
    const float rj2 = jac[i*3+2]-jac[p*3+2];
    #pragma unroll
    for (int r=0;r<3;++r) {
      const float c0=C[p][r*4+0], c1=C[p][r*4+1], c2=C[p][r*4+2], c3=C[p][r*4+3];
      C[i][r*4+0] = c0*R[i][0] + c1*R[i][3] + c2*R[i][6];
      C[i][r*4+1] = c0*R[i][1] + c1*R[i][4] + c2*R[i][7];
      C[i][r*4+2] = c0*R[i][2] + c1*R[i][5] + c2*R[i][8];
      C[i][r*4+3] = c0*rj0 + c1*rj1 + c2*rj2 + c3;
    }
  }

  float* rt = reltf + (size_t)b*60;
  #pragma unroll
  for (int j=0;j<5;++j) {
    const float jx=jac[j*3+0], jy=jac[j*3+1], jz=jac[j*3+2];
    #pragma unroll
    for (int r=0;r<3;++r) {
      const float m0=C[j][r*4+0], m1=C[j][r*4+1], m2=C[j][r*4+2], m3=C[j][r*4+3];
      rt[j*12+r*4+0]=m0; rt[j*12+r*4+1]=m1; rt[j*12+r*4+2]=m2;
      rt[j*12+r*4+3]=m3 - (m0*jx + m1*jy + m2*jz);
    }
  }

  const float c00=R[1][0], c10=R[1][3], c20=R[1][6];
  const float r00 = R[0][0]*c00 + R[0][1]*c10 + R[0][2]*c20;
  const float r10 = R[0][3]*c00 + R[0][4]*c10 + R[0][5]*c20;
  const float r20 = R[0][6]*c00 + R[0][7]*c10 + R[0][8]*c20;
  const float sy = sqrtf(r00*r00 + r10*r10);
  const float yang = atan2f(-r20, sy) * 57.29577951308232f;
  int y = (int)rintf(fminf(yang, 39.0f));
  if (y < 0) y = (y < -39) ? 78 : (39 - y);
  yidx[b] = y;
}

// ---- k3 (round-15 best): 128 batches x 64 verts, 256 threads, 33 KB LDS.
// thread = vert vl x 32 batches (bg = t>>6 wave-uniform -> aoff = b0 + bg*32).
// Per kk: A = 2x wave-uniform s_load_dwordx16; B = 1 conflict-free ds_read_b128;
// 96 FMA-instr. Epilogue fully unrolled (rule #20: static acc indices).
#define SROW 260    // 260%32==4 -> staging writes 4-way; reads conflict-free

template<int KL, bool POSE>
__device__ __forceinline__ void chunk_body(int k0, int t, int vl, int aoff, int m0,
    const float* __restrict__ At, const float* __restrict__ shdirs,
    const float* __restrict__ pdirs, float* shB, float (&acc)[32][3]) {
  __syncthreads();   // previous chunk fully consumed
  if (!POSE) {
    constexpr int Q = KL/2;             // KL even for all shape chunks
    constexpr int TOT = 192*Q;
    for (int i = t; i < TOT; i += 256) {
      const int q  = i % Q;
      const int ml = i / Q;             // 0..191
      const int v  = ml/3, c = ml - v*3;
      int m = m0 + ml; if (m > MCOLS-1) m = MCOLS-1;
      const float2 f = *reinterpret_cast<const float2*>(shdirs + (size_t)m*K1 + k0 + 2*q);
      shB[(2*q)*SROW + v*4 + c]   = f.x;
      shB[(2*q+1)*SROW + v*4 + c] = f.y;
    }
  } else {
    constexpr int TOT = 192*KL;
    for (int i = t; i < TOT; i += 256) {
      const int kk = i / 192;
      const int ml = i - kk*192;
      const int v  = ml/3, c = ml - v*3;
      int m = m0 + ml; if (m > MCOLS-1) m = MCOLS-1;
      shB[kk*SROW + v*4 + c] = pdirs[(size_t)(k0 - K1 + kk)*MCOLS + m];
    }
  }
  __syncthreads();
  #pragma unroll 2
  for (int kk = 0; kk < KL; ++kk) {
    const float* ap = At + (size_t)(k0+kk)*BATCH + aoff;   // wave-uniform -> s_load
    const floatx4 bv = *reinterpret_cast<const floatx4*>(shB + kk*SROW + vl*4);
    #pragma unroll
    for (int i=0;i<32;++i) {
      const float ai = ap[i];
      acc[i][0] = fmaf(ai, bv[0], acc[i][0]);
      acc[i][1] = fmaf(ai, bv[1], acc[i][1]);
      acc[i][2] = fmaf(ai, bv[2], acc[i][2]);
    }
  }
}

__launch_bounds__(256, 4)
__global__ void k3_valu(const float* __restrict__ At, const float* __restrict__ shdirs,
                        const float* __restrict__ pdirs, const float* __restrict__ vtemp,
                        const float* __restrict__ lbsw, const float* __restrict__ reltf,
                        float* __restrict__ vout) {
  __shared__ float shB[32*SROW];    // 33280 B -> 4 blocks/CU

  const int t  = threadIdx.x;
  const int vl = t & 63;
  const int bg = t >> 6;             // 0..3, wave-uniform
  const int v0 = blockIdx.x * 64;
  const int b0 = blockIdx.y * 128;
  const int m0 = v0*3;
  const int aoff = __builtin_amdgcn_readfirstlane(b0 + bg*32);

  float acc[32][3] = {};

  #pragma unroll 1
  for (int ch = 0; ch < 4; ++ch)
    chunk_body<32,false>(ch*32, t, vl, aoff, m0, At, shdirs, pdirs, shB, acc);
  chunk_body<22,false>(128, t, vl, aoff, m0, At, shdirs, pdirs, shB, acc);
  chunk_body<32,true >(150, t, vl, aoff, m0, At, shdirs, pdirs, shB, acc);
  chunk_body<4, true >(182, t, vl, aoff, m0, At, shdirs, pdirs, shB, acc);

  // epilogue: FULLY UNROLLED; rel_tf via wave-uniform scalar loads; LBS + store
  const int v = v0 + vl;
  if (v < NV) {
    float w5[5];
    #pragma unroll
    for (int j=0;j<5;++j) w5[j] = lbsw[(size_t)v*5 + j];
    const float tx = vtemp[(size_t)v*3+0];
    const float ty = vtemp[(size_t)v*3+1];
    const float tz = vtemp[(size_t)v*3+2];
    #pragma unroll
    for (int i=0;i<32;++i) {
      const float* rl = reltf + (size_t)(aoff + i)*60;   // wave-uniform -> s_load
      const float vx = acc[i][0]+tx, vy = acc[i][1]+ty, vz = acc[i][2]+tz;
      float o[3];
      #pragma unroll
      for (int r=0;r<3;++r) {
        float a0=0.f,a1=0.f,a2=0.f,a3=0.f;
        #pragma unroll
        for (int j=0;j<5;++j) {
          a0 = fmaf(w5[j], rl[j*12+r*4+0], a0);
          a1 = fmaf(w5[j], rl[j*12+r*4+1], a1);
          a2 = fmaf(w5[j], rl[j*12+r*4+2], a2);
          a3 = fmaf(w5[j], rl[j*12+r*4+3], a3);
        }
        o[r] = fmaf(a0, vx, fmaf(a1, vy, fmaf(a2, vz, a3)));
      }
      float* dst = vout + ((size_t)(aoff + i)*NV + v)*3;
      dst[0]=o[0]; dst[1]=o[1]; dst[2]=o[2];
    }
  }
}

// ---- k4: landmarks
__launch_bounds__(192)
__global__ void k4_landmarks(const float* __restrict__ verts, const int* __restrict__ faces,
                             const int* __restrict__ lmkf, const float* __restrict__ lmkb,
                             const int* __restrict__ dynf, const float* __restrict__ dynb,
                             const int* __restrict__ fullf, const float* __restrict__ fullb,
                             const int* __restrict__ yidx, float* __restrict__ out2d,
                             float* __restrict__ out3d) {
  const int b = blockIdx.x;
  const int t = threadIdx.x;
  if (t >= 136) return;
  const int which = t >= 68;
  const int i = which ? (t-68) : t;
  int fidx; float bw0,bw1,bw2;
  if (!which) {
    if (i < 17) {
      const int y = yidx[b];
      fidx = dynf[y*17 + i];
      const float* p = dynb + ((size_t)y*17 + i)*3;
      bw0=p[0]; bw1=p[1]; bw2=p[2];
    } else {
      fidx = lmkf[i-17];
      const float* p = lmkb + (size_t)(i-17)*3;
      bw0=p[0]; bw1=p[1]; bw2=p[2];
    }
  } else {
    fidx = fullf[i];
    const float* p = fullb + (size_t)i*3;
    bw0=p[0]; bw1=p[1]; bw2=p[2];
  }
  const int t0 = faces[fidx*3+0], t1 = faces[fidx*3+1], t2 = faces[fidx*3+2];
  const float* vb = verts + (size_t)b*NV*3;
  float* dst = (which ? out3d : out2d) + ((size_t)b*68 + i)*3;
  #pragma unroll
  for (int c=0;c<3;++c)
    dst[c] = vb[(size_t)t0*3+c]*bw0 + vb[(size_t)t1*3+c]*bw1 + vb[(size_t)t2*3+c]*bw2;
}

extern "C" void kernel_launch(void* const* d_in, const int* in_sizes, int n_in,
                              void* d_out, int out_size, void* d_ws, size_t ws_size,
                              hipStream_t stream) {
  const float* shape = (const float*)d_in[0];
  const float* expr  = (const float*)d_in[1];
  const float* pose  = (const float*)d_in[2];
  const float* vtemp = (const float*)d_in[3];
  const float* shdirs= (const float*)d_in[4];
  const float* pdirs = (const float*)d_in[5];
  const float* jreg  = (const float*)d_in[6];
  const float* lbsw  = (const float*)d_in[7];
  const float* neck  = (const float*)d_in[8];
  const float* eye   = (const float*)d_in[9];
  const int*   faces = (const int*)d_in[10];
  const int*   lmkf  = (const int*)d_in[11];
  const float* lmkb  = (const float*)d_in[12];
  const int*   dynf  = (const int*)d_in[13];
  const float* dynb  = (const float*)d_in[14];
  const int*   fullf = (const int*)d_in[15];
  const float* fullb = (const float*)d_in[16];

  float* wsf = (float*)d_ws;
  float* jsd     = wsf + WS_JSD;
  float* reltf   = wsf + WS_RELTF;
  int*   yidx    = (int*)(wsf + WS_Y);
  float* At      = wsf + WS_AT;
  float* partial = wsf + WS_PARTIAL;   // aliases At (dead before k2 writes At)

  float* vout  = (float*)d_out;
  float* out2d = vout + (size_t)BATCH*NV*3;
  float* out3d = out2d + (size_t)BATCH*68*3;

  hipLaunchKernelGGL(k1_jsd_partial, dim3(NCHUNK), dim3(512), 0, stream,
                     jreg, shdirs, vtemp, partial);
  hipLaunchKernelGGL(k1b_jsd_reduce, dim3(9), dim3(256), 0, stream, partial, jsd);
  hipLaunchKernelGGL(k2_pose, dim3(4), dim3(256), 0, stream,
                     shape, expr, pose, neck, eye, jsd, At, reltf, yidx);
  hipLaunchKernelGGL(k3_valu, dim3(80, BATCH/128), dim3(256), 0, stream,
                     At, shdirs, pdirs, vtemp, lbsw, reltf, vout);
  hipLaunchKernelGGL(k4_landmarks, dim3(BATCH), dim3(192), 0, stream,
                     vout, faces, lmkf, lmkb, dynf, dynb, fullf, fullb, yidx, out2d, out3d);
}